// Round 15
// baseline (1820.279 us; speedup 1.0000x reference)
//
#include <hip/hip_runtime.h>
#include <stdint.h>

#define D 4096

typedef __attribute__((ext_vector_type(8))) short bf16x8;
typedef __attribute__((ext_vector_type(4))) float f32x4;
typedef __attribute__((ext_vector_type(16))) float f32x16;

#define MFMA16 __builtin_amdgcn_mfma_f32_16x16x32_bf16
#define MFMA32 __builtin_amdgcn_mfma_f32_32x32x16_bf16

__device__ __forceinline__ float sgnf(float z) {
    return (z > 0.f) ? 1.f : ((z < 0.f) ? -1.f : 0.f);
}

// HW pair convert+pack: dst = { lo16: bf16(a), hi16: bf16(b) }  (gfx950)
__device__ __forceinline__ uint cvtpk(float a, float b) {
    uint r;
    asm("v_cvt_pk_bf16_f32 %0, %1, %2" : "=v"(r) : "v"(a), "v"(b));
    return r;
}
// triple-split a pair of fp32 into packed h/m/l bf16 pairs (exact residuals).
__device__ __forceinline__ void split3_pk(float f0, float f1, uint& hp, uint& mp, uint& lp) {
    hp = cvtpk(f0, f1);
    float h0 = __uint_as_float(hp << 16);
    float h1 = __uint_as_float(hp & 0xffff0000u);
    float r0 = f0 - h0, r1 = f1 - h1;
    mp = cvtpk(r0, r1);
    float m0 = __uint_as_float(mp << 16);
    float m1 = __uint_as_float(mp & 0xffff0000u);
    lp = cvtpk(r0 - m0, r1 - m1);
}

// ---- forward GEMV: bit-exact emulation of numpy-f32 (OpenBLAS AVX2 sgemv_t) ----
// DO NOT TOUCH — bit-exactness of z1/z2/z3 vs the reference is load-bearing.
__global__ __launch_bounds__(256) void gemv_blas8(const float* __restrict__ W,
                                                  const float* __restrict__ v,
                                                  const float* __restrict__ bias,
                                                  float* __restrict__ z,
                                                  float* __restrict__ act, int doAct) {
    int gid = blockIdx.x * 256 + threadIdx.x;
    int row = gid >> 3;
    int l = gid & 7;
    const float* wr = W + (size_t)row * D;
    float acc = 0.f;
    for (int k = l; k < D; k += 8) acc = fmaf(wr[k], v[k], acc);
    float b = acc + __shfl_xor(acc, 4);
    float c = b + __shfl_xor(b, 1);
    float s = c + __shfl_xor(c, 2);
    if (l == 0) {
        z[row] = s;
        if (doAct) act[row] = fmaxf(s + bias[row], 0.f);
    }
}

__global__ __launch_bounds__(256) void vecprep32(const float* __restrict__ z1,
                                                 const float* __restrict__ z2,
                                                 const float* __restrict__ z3,
                                                 const float* __restrict__ a1,
                                                 const float* __restrict__ a2,
                                                 const float* __restrict__ b3,
                                                 float* __restrict__ out,
                                                 float* __restrict__ s3,
                                                 float* __restrict__ g2,
                                                 float* __restrict__ g1) {
    int i = blockIdx.x * 256 + threadIdx.x;
    float z3v = z3[i];
    float o = z3v + b3[i];
    out[i] = o;
    s3[i] = o / (z3v + 1e-9f * sgnf(z3v));
    float z2v = z2[i];
    g2[i] = a2[i] / (z2v + 1e-9f * sgnf(z2v));
    float z1v = z1[i];
    g1[i] = a1[i] / (z1v + 1e-9f * sgnf(z1v));
}

// ================= pre-split planes (blocked for 32x32x16 fragments) =================
// Plane tile (bi, kt) = 4096 contiguous ushorts at ((bi*128 + kt)*4096).
// Cell (rb in [0,4), ks in [0,2), lane in [0,64)): offset (rb*2+ks)*512 + lane*8 + j.
// Element: row = bi*128 + rb*32 + (lane&31); k = kt*32 + ks*16 + (lane>>5)*8 + j.
__global__ __launch_bounds__(256) void prepBT(const float* __restrict__ W,
                                              ushort* __restrict__ Ph,
                                              ushort* __restrict__ Pm,
                                              ushort* __restrict__ Pl) {
    size_t ci = (size_t)blockIdx.x * 256 + threadIdx.x;
    int c = (int)(ci & 511);
    int l = c & 63, sub = c >> 6;
    int rb = sub >> 1, kss = sub & 1;
    int kt = (int)((ci >> 9) & 127);
    int bi = (int)(ci >> 16);
    int col = bi * 128 + rb * 32 + (l & 31);
    int k0 = kt * 32 + kss * 16 + (l >> 5) * 8;
    float v[8];
#pragma unroll
    for (int j = 0; j < 8; j++) v[j] = W[(size_t)(k0 + j) * D + col];
    uint hp[4], mp[4], lp[4];
#pragma unroll
    for (int j = 0; j < 4; j++) split3_pk(v[2 * j], v[2 * j + 1], hp[j], mp[j], lp[j]);
    size_t dst = ci * 8;
    uint4 u;
    u.x = hp[0]; u.y = hp[1]; u.z = hp[2]; u.w = hp[3]; *(uint4*)(Ph + dst) = u;
    u.x = mp[0]; u.y = mp[1]; u.z = mp[2]; u.w = mp[3]; *(uint4*)(Pm + dst) = u;
    u.x = lp[0]; u.y = lp[1]; u.z = lp[2]; u.w = lp[3]; *(uint4*)(Pl + dst) = u;
}

// gemm_bs (32x32x16): O[i,c] = (Sum_k Asc[i,k]*B[k,c]) * cs[c]; A fp32 split
// in-kernel cooperatively (cvt_pk), B pre-split blocked planes, DMA-staged
// double-buffered, counted vmcnt. 6 products: hh+hm+mh+mm+hl+lh.
// 128x128 tile, 4 waves (2x2 of 64x64; each wave 2x2 frags of 32x32).
// MODE 0: fp32 O.  MODE 1: write O as 3 blocked bf16 planes (same plane layout).
template <int SCALED, int MODE>
__global__ __launch_bounds__(256, 2) void gemm_bs(const float* __restrict__ A,
                                                  const ushort* __restrict__ Bh,
                                                  const ushort* __restrict__ Bm_,
                                                  const ushort* __restrict__ Bl_,
                                                  const float* __restrict__ rs,
                                                  const float* __restrict__ ks,
                                                  const float* __restrict__ cs,
                                                  float* __restrict__ O,
                                                  ushort* __restrict__ Cph,
                                                  ushort* __restrict__ Cpm,
                                                  ushort* __restrict__ Cpl_) {
    __shared__ ushort ldsA[3][4096];
    __shared__ ushort ldsB[2][3][4096];
    int t = threadIdx.x;
    int lane = t & 63, wv = t >> 6;
    int wr = wv >> 1, wc = wv & 1;
    int cl = lane & 31, lh = lane >> 5;
    int bx = blockIdx.x, by = blockIdx.y;
    size_t row0 = (size_t)by * 128, col0 = (size_t)bx * 128;

    int rr = t >> 1;   // staged A row 0..127
    int kh = t & 1;    // which 16-k half (ks)
    int cellb0 = (((rr >> 5) * 2 + kh) * 64 + (rr & 31)) * 8;        // k-sub j=0..7  (lane<32)
    int cellb1 = (((rr >> 5) * 2 + kh) * 64 + (rr & 31) + 32) * 8;   // k-sub j=8..15 (lane>=32)

    f32x16 acc[2][2];
#pragma unroll
    for (int m = 0; m < 2; m++)
#pragma unroll
        for (int n = 0; n < 2; n++)
#pragma unroll
            for (int q = 0; q < 16; q++) acc[m][n][q] = 0.f;

    float rsv = SCALED ? rs[row0 + rr] : 0.f;
    const float* arow = A + (row0 + rr) * (size_t)D;

    float av[16];
    auto LOADA = [&](int k0) {
        const float4* pa = (const float4*)(arow + k0 + kh * 16);
#pragma unroll
        for (int qq = 0; qq < 4; qq++) {
            float4 w = pa[qq];
            av[qq * 4 + 0] = w.x; av[qq * 4 + 1] = w.y;
            av[qq * 4 + 2] = w.z; av[qq * 4 + 3] = w.w;
        }
        if (SCALED) {
            const float4* pk = (const float4*)(ks + k0 + kh * 16);
#pragma unroll
            for (int qq = 0; qq < 4; qq++) {
                float4 kk = pk[qq];
                av[qq * 4 + 0] *= rsv * kk.x; av[qq * 4 + 1] *= rsv * kk.y;
                av[qq * 4 + 2] *= rsv * kk.z; av[qq * 4 + 3] *= rsv * kk.w;
            }
        }
    };

    auto DMAB = [&](int kt, int buf) {
        size_t bt = ((size_t)bx * 128 + kt) * 4096;
        const ushort* bsrc[3] = {Bh + bt, Bm_ + bt, Bl_ + bt};
#pragma unroll
        for (int p = 0; p < 3; p++) {
            __builtin_amdgcn_global_load_lds(
                (const __attribute__((address_space(1))) uint32_t*)(bsrc[p] + (size_t)t * 8),
                (__attribute__((address_space(3))) uint32_t*)(&ldsB[buf][p][t * 8]), 16, 0, 0);
            __builtin_amdgcn_global_load_lds(
                (const __attribute__((address_space(1))) uint32_t*)(bsrc[p] + (size_t)(t + 256) * 8),
                (__attribute__((address_space(3))) uint32_t*)(&ldsB[buf][p][(t + 256) * 8]), 16, 0, 0);
        }
    };

    auto SPLITA = [&]() {
        uint hp[8], mp[8], lp[8];
#pragma unroll
        for (int j = 0; j < 8; j++) split3_pk(av[2 * j], av[2 * j + 1], hp[j], mp[j], lp[j]);
        uint4 u;
        u.x = hp[0]; u.y = hp[1]; u.z = hp[2]; u.w = hp[3]; *(uint4*)&ldsA[0][cellb0] = u;
        u.x = hp[4]; u.y = hp[5]; u.z = hp[6]; u.w = hp[7]; *(uint4*)&ldsA[0][cellb1] = u;
        u.x = mp[0]; u.y = mp[1]; u.z = mp[2]; u.w = mp[3]; *(uint4*)&ldsA[1][cellb0] = u;
        u.x = mp[4]; u.y = mp[5]; u.z = mp[6]; u.w = mp[7]; *(uint4*)&ldsA[1][cellb1] = u;
        u.x = lp[0]; u.y = lp[1]; u.z = lp[2]; u.w = lp[3]; *(uint4*)&ldsA[2][cellb0] = u;
        u.x = lp[4]; u.y = lp[5]; u.z = lp[6]; u.w = lp[7]; *(uint4*)&ldsA[2][cellb1] = u;
    };

    auto MFMA_PHASE = [&](int buf) {
#pragma unroll
        for (int ksq = 0; ksq < 2; ++ksq) {
            bf16x8 ah[2], am[2], al[2], bh[2], bm[2], bl[2];
#pragma unroll
            for (int m = 0; m < 2; m++) {
                int base = ((wr * 2 + m) * 2 + ksq) * 512 + lane * 8;
                ah[m] = *(const bf16x8*)&ldsA[0][base];
                am[m] = *(const bf16x8*)&ldsA[1][base];
                al[m] = *(const bf16x8*)&ldsA[2][base];
            }
#pragma unroll
            for (int n = 0; n < 2; n++) {
                int base = ((wc * 2 + n) * 2 + ksq) * 512 + lane * 8;
                bh[n] = *(const bf16x8*)&ldsB[buf][0][base];
                bm[n] = *(const bf16x8*)&ldsB[buf][1][base];
                bl[n] = *(const bf16x8*)&ldsB[buf][2][base];
            }
#pragma unroll
            for (int m = 0; m < 2; m++)
#pragma unroll
                for (int n = 0; n < 2; n++) {
                    acc[m][n] = MFMA32(ah[m], bh[n], acc[m][n], 0, 0, 0);
                    acc[m][n] = MFMA32(ah[m], bm[n], acc[m][n], 0, 0, 0);
                    acc[m][n] = MFMA32(am[m], bh[n], acc[m][n], 0, 0, 0);
                    acc[m][n] = MFMA32(am[m], bm[n], acc[m][n], 0, 0, 0);
                    acc[m][n] = MFMA32(ah[m], bl[n], acc[m][n], 0, 0, 0);
                    acc[m][n] = MFMA32(al[m], bh[n], acc[m][n], 0, 0, 0);
                }
        }
    };

    const int NT = D / 32;

    LOADA(0);
    SPLITA();
    DMAB(0, 0);
    LOADA(32);
    DMAB(1, 1);
    asm volatile("s_waitcnt vmcnt(6) lgkmcnt(0)" ::: "memory");
    __builtin_amdgcn_s_barrier();
    __builtin_amdgcn_sched_barrier(0);

    for (int tt = 0; tt < NT; ++tt) {
        MFMA_PHASE(tt & 1);
        __builtin_amdgcn_sched_barrier(0);
        __builtin_amdgcn_s_barrier();
        __builtin_amdgcn_sched_barrier(0);
        if (tt < NT - 1) {
            SPLITA();
            if (tt < NT - 2) {
                LOADA((tt + 2) * 32);
                DMAB(tt + 2, tt & 1);
                asm volatile("s_waitcnt vmcnt(6) lgkmcnt(0)" ::: "memory");
            } else {
                asm volatile("s_waitcnt vmcnt(0) lgkmcnt(0)" ::: "memory");
            }
            __builtin_amdgcn_s_barrier();
            __builtin_amdgcn_sched_barrier(0);
        }
    }

    float csv[2];
#pragma unroll
    for (int n = 0; n < 2; n++) csv[n] = cs[col0 + wc * 64 + n * 32 + cl];
#pragma unroll
    for (int m = 0; m < 2; m++)
#pragma unroll
        for (int n = 0; n < 2; n++) {
            if (MODE == 0) {
#pragma unroll
                for (int reg = 0; reg < 16; ++reg) {
                    size_t grow = row0 + wr * 64 + m * 32 + (reg & 3) + 8 * (reg >> 2) + 4 * lh;
                    size_t gcol = col0 + wc * 64 + n * 32 + cl;
                    O[grow * D + gcol] = acc[m][n][reg] * csv[n];
                }
            } else {
                // write C as blocked planes (layout prepBT writes): for element
                // (i, k): bi=i>>7, rb=(i>>5)&3, cell-lane=(i&31)+32*((k>>3)&1),
                // ks=(k>>4)&1, j=k&7.
                int k = (int)(col0 + wc * 64 + n * 32 + cl);
                int ktc = k >> 5, ksc = (k >> 4) & 1, jc = k & 7;
                int lhi = ((k >> 3) & 1) * 32;
#pragma unroll
                for (int pr = 0; pr < 8; ++pr) {
                    float v0 = acc[m][n][2 * pr] * csv[n];
                    float v1 = acc[m][n][2 * pr + 1] * csv[n];
                    uint hp, mp, lp;
                    split3_pk(v0, v1, hp, mp, lp);
#pragma unroll
                    for (int s = 0; s < 2; s++) {
                        int reg = 2 * pr + s;
                        int i = (int)(row0 + wr * 64 + m * 32 + (reg & 3) + 8 * (reg >> 2) + 4 * lh);
                        int bi2 = i >> 7, rb2 = (i >> 5) & 3;
                        int lcell = (i & 31) + lhi;
                        size_t off = (((size_t)bi2 * 128 + ktc) * 512 +
                                      (size_t)((rb2 * 2 + ksc) * 64 + lcell)) * 8 + jc;
                        Cph[off] = (ushort)(hp >> (16 * s));
                        Cpm[off] = (ushort)(mp >> (16 * s));
                        Cpl_[off] = (ushort)(lp >> (16 * s));
                    }
                }
            }
        }
}

// gemm_ab2 (32x32x16): BOTH operands pre-split blocked planes, all-DMA (zero
// K-loop VALU), 128x128 tile, 256 threads, 4 waves. A single-buffered (24 KB),
// B double-buffered (48 KB) -> 72 KB LDS -> 2 blocks/CU. Counted vmcnt.
__global__ __launch_bounds__(256, 2) void gemm_ab2(const ushort* __restrict__ Ah,
                                                   const ushort* __restrict__ Am_,
                                                   const ushort* __restrict__ Al_,
                                                   const ushort* __restrict__ Bh,
                                                   const ushort* __restrict__ Bm_,
                                                   const ushort* __restrict__ Bl_,
                                                   const float* __restrict__ cs,
                                                   float* __restrict__ O) {
    __shared__ ushort ldsA[3][4096];
    __shared__ ushort ldsB[2][3][4096];
    int t = threadIdx.x;
    int lane = t & 63, wv = t >> 6;
    int wr = wv >> 1, wc = wv & 1;
    int cl = lane & 31, lh = lane >> 5;
    int bx = blockIdx.x, by = blockIdx.y;
    size_t row0 = (size_t)by * 128, col0 = (size_t)bx * 128;

    f32x16 acc[2][2];
#pragma unroll
    for (int m = 0; m < 2; m++)
#pragma unroll
        for (int n = 0; n < 2; n++)
#pragma unroll
            for (int q = 0; q < 16; q++) acc[m][n][q] = 0.f;

    auto DMAA = [&](int kt) {
        size_t at = ((size_t)by * 128 + kt) * 4096;
        const ushort* asrc[3] = {Ah + at, Am_ + at, Al_ + at};
#pragma unroll
        for (int p = 0; p < 3; p++) {
            __builtin_amdgcn_global_load_lds(
                (const __attribute__((address_space(1))) uint32_t*)(asrc[p] + (size_t)t * 8),
                (__attribute__((address_space(3))) uint32_t*)(&ldsA[p][t * 8]), 16, 0, 0);
            __builtin_amdgcn_global_load_lds(
                (const __attribute__((address_space(1))) uint32_t*)(asrc[p] + (size_t)(t + 256) * 8),
                (__attribute__((address_space(3))) uint32_t*)(&ldsA[p][(t + 256) * 8]), 16, 0, 0);
        }
    };

    auto DMAB = [&](int kt, int buf) {
        size_t bt = ((size_t)bx * 128 + kt) * 4096;
        const ushort* bsrc[3] = {Bh + bt, Bm_ + bt, Bl_ + bt};
#pragma unroll
        for (int p = 0; p < 3; p++) {
            __builtin_amdgcn_global_load_lds(
                (const __attribute__((address_space(1))) uint32_t*)(bsrc[p] + (size_t)t * 8),
                (__attribute__((address_space(3))) uint32_t*)(&ldsB[buf][p][t * 8]), 16, 0, 0);
            __builtin_amdgcn_global_load_lds(
                (const __attribute__((address_space(1))) uint32_t*)(bsrc[p] + (size_t)(t + 256) * 8),
                (__attribute__((address_space(3))) uint32_t*)(&ldsB[buf][p][(t + 256) * 8]), 16, 0, 0);
        }
    };

    auto MFMA_PHASE = [&](int buf) {
#pragma unroll
        for (int ksq = 0; ksq < 2; ++ksq) {
            bf16x8 ah[2], am[2], al[2], bh[2], bm[2], bl[2];
#pragma unroll
            for (int m = 0; m < 2; m++) {
                int base = ((wr * 2 + m) * 2 + ksq) * 512 + lane * 8;
                ah[m] = *(const bf16x8*)&ldsA[0][base];
                am[m] = *(const bf16x8*)&ldsA[1][base];
                al[m] = *(const bf16x8*)&ldsA[2][base];
            }
#pragma unroll
            for (int n = 0; n < 2; n++) {
                int base = ((wc * 2 + n) * 2 + ksq) * 512 + lane * 8;
                bh[n] = *(const bf16x8*)&ldsB[buf][0][base];
                bm[n] = *(const bf16x8*)&ldsB[buf][1][base];
                bl[n] = *(const bf16x8*)&ldsB[buf][2][base];
            }
#pragma unroll
            for (int m = 0; m < 2; m++)
#pragma unroll
                for (int n = 0; n < 2; n++) {
                    acc[m][n] = MFMA32(ah[m], bh[n], acc[m][n], 0, 0, 0);
                    acc[m][n] = MFMA32(ah[m], bm[n], acc[m][n], 0, 0, 0);
                    acc[m][n] = MFMA32(am[m], bh[n], acc[m][n], 0, 0, 0);
                    acc[m][n] = MFMA32(am[m], bm[n], acc[m][n], 0, 0, 0);
                    acc[m][n] = MFMA32(ah[m], bl[n], acc[m][n], 0, 0, 0);
                    acc[m][n] = MFMA32(al[m], bh[n], acc[m][n], 0, 0, 0);
                }
        }
    };

    const int NT = D / 32;

    DMAA(0);
    DMAB(0, 0);
    DMAB(1, 1);
    asm volatile("s_waitcnt vmcnt(6)" ::: "memory");  // A0 + B0 done, B1 in flight
    __builtin_amdgcn_sched_barrier(0);
    __builtin_amdgcn_s_barrier();
    __builtin_amdgcn_sched_barrier(0);

    for (int tt = 0; tt < NT; ++tt) {
        MFMA_PHASE(tt & 1);
        __builtin_amdgcn_sched_barrier(0);
        __builtin_amdgcn_s_barrier();
        __builtin_amdgcn_sched_barrier(0);
        if (tt < NT - 1) {
            DMAA(tt + 1);
            if (tt < NT - 2) {
                DMAB(tt + 2, tt & 1);
                asm volatile("s_waitcnt vmcnt(6)" ::: "memory");
            } else {
                asm volatile("s_waitcnt vmcnt(0)" ::: "memory");
            }
            __builtin_amdgcn_sched_barrier(0);
            __builtin_amdgcn_s_barrier();
            __builtin_amdgcn_sched_barrier(0);
        }
    }

    float csv[2];
#pragma unroll
    for (int n = 0; n < 2; n++) csv[n] = cs[col0 + wc * 64 + n * 32 + cl];
#pragma unroll
    for (int m = 0; m < 2; m++)
#pragma unroll
        for (int n = 0; n < 2; n++)
#pragma unroll
            for (int reg = 0; reg < 16; ++reg) {
                size_t grow = row0 + wr * 64 + m * 32 + (reg & 3) + 8 * (reg >> 2) + 4 * lh;
                size_t gcol = col0 + wc * 64 + n * 32 + cl;
                O[grow * D + gcol] = acc[m][n][reg] * csv[n];
            }
}

// ================= small-ws fallback (R5-proven, 16x16) =================
constexpr int BM = 128, BN = 128, LDK = 40;

template <int SCALED>
__global__ __launch_bounds__(256, 2) void gemm3(const float* __restrict__ A,
                                                const float* __restrict__ B,
                                                const float* __restrict__ rs,
                                                const float* __restrict__ ks,
                                                const float* __restrict__ cs,
                                                float* __restrict__ O) {
    __shared__ ushort Ahs[BM][LDK], Ams[BM][LDK], Als[BM][LDK];
    __shared__ ushort Bhs[BN][LDK], Bms[BN][LDK], Bls[BN][LDK];
    int t = threadIdx.x;
    int lane = t & 63, wv = t >> 6;
    int wr = wv >> 1, wc = wv & 1;
    int r = lane & 15, g = lane >> 4;
    size_t row0 = (size_t)blockIdx.y * BM;
    size_t col0 = (size_t)blockIdx.x * BN;
    int sArow = t >> 1, sAk = (t & 1) * 16, sBcol = t & 127, sBk = (t >> 7) * 16;

    f32x4 acc[4][4];
#pragma unroll
    for (int m = 0; m < 4; m++)
#pragma unroll
        for (int n = 0; n < 4; n++) acc[m][n] = (f32x4){0.f, 0.f, 0.f, 0.f};

    float av[16], bv[16];
    auto LOADT = [&](int k0) {
        const float4* pa = (const float4*)(A + (row0 + sArow) * (size_t)D + k0 + sAk);
#pragma unroll
        for (int qq = 0; qq < 4; qq++) {
            float4 w = pa[qq];
            av[qq * 4 + 0] = w.x; av[qq * 4 + 1] = w.y; av[qq * 4 + 2] = w.z; av[qq * 4 + 3] = w.w;
        }
        if (SCALED) {
            float rsv = rs[row0 + sArow];
            const float4* pk = (const float4*)(ks + k0 + sAk);
#pragma unroll
            for (int qq = 0; qq < 4; qq++) {
                float4 kk = pk[qq];
                av[qq * 4 + 0] *= rsv * kk.x; av[qq * 4 + 1] *= rsv * kk.y;
                av[qq * 4 + 2] *= rsv * kk.z; av[qq * 4 + 3] *= rsv * kk.w;
            }
        }
        const float* pb = B + ((size_t)k0 + sBk) * D + col0 + sBcol;
#pragma unroll
        for (int kk = 0; kk < 16; kk++) bv[kk] = pb[(size_t)kk * D];
    };

    LOADT(0);
    for (int kt = 0; kt < D / 32; ++kt) {
        __syncthreads();
        {
            uint hp[8], mp[8], lp[8];
#pragma unroll
            for (int j = 0; j < 8; j++) split3_pk(av[2 * j], av[2 * j + 1], hp[j], mp[j], lp[j]);
            uint4 u;
            u.x = hp[0]; u.y = hp[1]; u.z = hp[2]; u.w = hp[3]; *(uint4*)&Ahs[sArow][sAk] = u;
            u.x = hp[4]; u.y = hp[5]; u.z = hp[6]; u.w = hp[7]; *(uint4*)&Ahs[sArow][sAk + 8] = u;
            u.x = mp[0]; u.y = mp[1]; u.z = mp[2]; u.w = mp[3]; *(uint4*)&Ams[sArow][sAk] = u;
            u.x = mp[4]; u.y = mp[5]; u.z = mp[6]; u.w = mp[7]; *(uint4*)&Ams[sArow][sAk + 8] = u;
            u.x = lp[0]; u.y = lp[1]; u.z = lp[2]; u.w = lp[3]; *(uint4*)&Als[sArow][sAk] = u;
            u.x = lp[4]; u.y = lp[5]; u.z = lp[6]; u.w = lp[7]; *(uint4*)&Als[sArow][sAk + 8] = u;
        }
        {
            uint hp[8], mp[8], lp[8];
#pragma unroll
            for (int j = 0; j < 8; j++) split3_pk(bv[2 * j], bv[2 * j + 1], hp[j], mp[j], lp[j]);
            uint4 u;
            u.x = hp[0]; u.y = hp[1]; u.z = hp[2]; u.w = hp[3]; *(uint4*)&Bhs[sBcol][sBk] = u;
            u.x = hp[4]; u.y = hp[5]; u.z = hp[6]; u.w = hp[7]; *(uint4*)&Bhs[sBcol][sBk + 8] = u;
            u.x = mp[0]; u.y = mp[1]; u.z = mp[2]; u.w = mp[3]; *(uint4*)&Bms[sBcol][sBk] = u;
            u.x = mp[4]; u.y = mp[5]; u.z = mp[6]; u.w = mp[7]; *(uint4*)&Bms[sBcol][sBk + 8] = u;
            u.x = lp[0]; u.y = lp[1]; u.z = lp[2]; u.w = lp[3]; *(uint4*)&Bls[sBcol][sBk] = u;
            u.x = lp[4]; u.y = lp[5]; u.z = lp[6]; u.w = lp[7]; *(uint4*)&Bls[sBcol][sBk + 8] = u;
        }
        __syncthreads();
        if (kt + 1 < D / 32) LOADT((kt + 1) * 32);

        bf16x8 bh[4], bm[4], bl[4];
#pragma unroll
        for (int n = 0; n < 4; n++) {
            bh[n] = *(const bf16x8*)&Bhs[wc * 64 + n * 16 + r][g * 8];
            bm[n] = *(const bf16x8*)&Bms[wc * 64 + n * 16 + r][g * 8];
            bl[n] = *(const bf16x8*)&Bls[wc * 64 + n * 16 + r][g * 8];
        }
#pragma unroll
        for (int m = 0; m < 4; m++) {
            bf16x8 ah = *(const bf16x8*)&Ahs[wr * 64 + m * 16 + r][g * 8];
            bf16x8 am = *(const bf16x8*)&Ams[wr * 64 + m * 16 + r][g * 8];
            bf16x8 al = *(const bf16x8*)&Als[wr * 64 + m * 16 + r][g * 8];
#pragma unroll
            for (int n = 0; n < 4; n++) {
                acc[m][n] = MFMA16(ah, bh[n], acc[m][n], 0, 0, 0);
                acc[m][n] = MFMA16(ah, bm[n], acc[m][n], 0, 0, 0);
                acc[m][n] = MFMA16(am, bh[n], acc[m][n], 0, 0, 0);
                acc[m][n] = MFMA16(am, bm[n], acc[m][n], 0, 0, 0);
                acc[m][n] = MFMA16(ah, bl[n], acc[m][n], 0, 0, 0);
                acc[m][n] = MFMA16(al, bh[n], acc[m][n], 0, 0, 0);
            }
        }
    }
    float csv[4];
#pragma unroll
    for (int n = 0; n < 4; n++) csv[n] = cs[col0 + wc * 64 + n * 16 + r];
#pragma unroll
    for (int m = 0; m < 4; m++)
#pragma unroll
        for (int n = 0; n < 4; n++)
#pragma unroll
            for (int j = 0; j < 4; j++) {
                size_t grow = row0 + wr * 64 + m * 16 + g * 4 + j;
                size_t gcol = col0 + wc * 64 + n * 16 + r;
                O[grow * D + gcol] = acc[m][n][j] * csv[n];
            }
}

extern "C" void kernel_launch(void* const* d_in, const int* in_sizes, int n_in,
                              void* d_out, int out_size, void* d_ws, size_t ws_size,
                              hipStream_t stream) {
    const float* x = (const float*)d_in[0];
    const float* W1 = (const float*)d_in[1];
    const float* b1 = (const float*)d_in[2];
    const float* W2 = (const float*)d_in[3];
    const float* b2 = (const float*)d_in[4];
    const float* W3 = (const float*)d_in[5];
    const float* b3 = (const float*)d_in[6];

    float* out = (float*)d_out;
    float* Rout = out + D;

    char* ws = (char*)d_ws;
    float* z1 = (float*)ws;
    float* z2 = z1 + D;
    float* z3 = z2 + D;
    float* a1 = z3 + D;
    float* a2 = a1 + D;
    float* s3 = a2 + D;
    float* g2 = s3 + D;
    float* g1 = g2 + D;
    size_t smallB = (size_t)D * 8 * sizeof(float);

    const size_t PL = (size_t)D * D;                     // ushorts per plane (32 MB)
    size_t planesB = 3 * PL * sizeof(ushort);            // 96 MB
    size_t cB = (size_t)D * D * sizeof(float);           // 64 MB
    size_t need2 = smallB + 2 * planesB + 256;           // ~192.13 MB (proven available)
    size_t need1 = smallB + planesB + cB + 256;          // ~160.13 MB

    // forward pass — bit-exact numpy-f32 emulation (unchanged)
    gemv_blas8<<<(D * 8) / 256, 256, 0, stream>>>(W1, x, b1, z1, a1, 1);
    gemv_blas8<<<(D * 8) / 256, 256, 0, stream>>>(W2, a1, b2, z2, a2, 1);
    gemv_blas8<<<(D * 8) / 256, 256, 0, stream>>>(W3, a2, b3, z3, nullptr, 0);
    vecprep32<<<D / 256, 256, 0, stream>>>(z1, z2, z3, a1, a2, b3, out, s3, g2, g1);

    dim3 gg(D / 128, D / 128);
    int pgrid = (int)((PL / 8) / 256);
    if (ws_size >= need2) {
        ushort* Bpl = (ushort*)(ws + smallB);
        ushort* Cpl = Bpl + 3 * PL;
        prepBT<<<pgrid, 256, 0, stream>>>(W2, Bpl, Bpl + PL, Bpl + 2 * PL);
        gemm_bs<1, 1><<<gg, 256, 0, stream>>>(W3, Bpl, Bpl + PL, Bpl + 2 * PL,
                                              s3, g2, g1, nullptr,
                                              Cpl, Cpl + PL, Cpl + 2 * PL);
        prepBT<<<pgrid, 256, 0, stream>>>(W1, Bpl, Bpl + PL, Bpl + 2 * PL);
        gemm_ab2<<<gg, 256, 0, stream>>>(Cpl, Cpl + PL, Cpl + 2 * PL,
                                         Bpl, Bpl + PL, Bpl + 2 * PL, x, Rout);
    } else if (ws_size >= need1) {
        ushort* Bpl = (ushort*)(ws + smallB);
        float* C = (float*)(ws + smallB + planesB);
        prepBT<<<pgrid, 256, 0, stream>>>(W2, Bpl, Bpl + PL, Bpl + 2 * PL);
        gemm_bs<1, 0><<<gg, 256, 0, stream>>>(W3, Bpl, Bpl + PL, Bpl + 2 * PL,
                                              s3, g2, g1, C, nullptr, nullptr, nullptr);
        prepBT<<<pgrid, 256, 0, stream>>>(W1, Bpl, Bpl + PL, Bpl + 2 * PL);
        gemm_bs<0, 0><<<gg, 256, 0, stream>>>(C, Bpl, Bpl + PL, Bpl + 2 * PL,
                                              nullptr, nullptr, x, Rout, nullptr, nullptr, nullptr);
    } else {
        float* C = (float*)(ws + smallB);
        gemm3<1><<<gg, 256, 0, stream>>>(W3, W2, s3, g2, g1, C);
        gemm3<0><<<gg, 256, 0, stream>>>(C, W1, nullptr, nullptr, x, Rout);
    }
}

// Round 16
// 1640.420 us; speedup vs baseline: 1.1096x; 1.1096x over previous
//
#include <hip/hip_runtime.h>
#include <stdint.h>

#define D 4096

typedef __attribute__((ext_vector_type(8))) short bf16x8;
typedef __attribute__((ext_vector_type(4))) float f32x4;

#define MFMA16 __builtin_amdgcn_mfma_f32_16x16x32_bf16

__device__ __forceinline__ float sgnf(float z) {
    return (z > 0.f) ? 1.f : ((z < 0.f) ? -1.f : 0.f);
}

// HW pair convert+pack: dst = { lo16: bf16(a), hi16: bf16(b) }  (gfx950)
__device__ __forceinline__ uint cvtpk(float a, float b) {
    uint r;
    asm("v_cvt_pk_bf16_f32 %0, %1, %2" : "=v"(r) : "v"(a), "v"(b));
    return r;
}
// triple-split a pair of fp32 into packed h/m/l bf16 pairs (exact residuals).
__device__ __forceinline__ void split3_pk(float f0, float f1, uint& hp, uint& mp, uint& lp) {
    hp = cvtpk(f0, f1);
    float h0 = __uint_as_float(hp << 16);
    float h1 = __uint_as_float(hp & 0xffff0000u);
    float r0 = f0 - h0, r1 = f1 - h1;
    mp = cvtpk(r0, r1);
    float m0 = __uint_as_float(mp << 16);
    float m1 = __uint_as_float(mp & 0xffff0000u);
    lp = cvtpk(r0 - m0, r1 - m1);
}

// ---- forward GEMV: bit-exact emulation of numpy-f32 (OpenBLAS AVX2 sgemv_t) ----
// DO NOT TOUCH — bit-exactness of z1/z2/z3 vs the reference is load-bearing.
__global__ __launch_bounds__(256) void gemv_blas8(const float* __restrict__ W,
                                                  const float* __restrict__ v,
                                                  const float* __restrict__ bias,
                                                  float* __restrict__ z,
                                                  float* __restrict__ act, int doAct) {
    int gid = blockIdx.x * 256 + threadIdx.x;
    int row = gid >> 3;
    int l = gid & 7;
    const float* wr = W + (size_t)row * D;
    float acc = 0.f;
    for (int k = l; k < D; k += 8) acc = fmaf(wr[k], v[k], acc);
    float b = acc + __shfl_xor(acc, 4);
    float c = b + __shfl_xor(b, 1);
    float s = c + __shfl_xor(c, 2);
    if (l == 0) {
        z[row] = s;
        if (doAct) act[row] = fmaxf(s + bias[row], 0.f);
    }
}

__global__ __launch_bounds__(256) void vecprep32(const float* __restrict__ z1,
                                                 const float* __restrict__ z2,
                                                 const float* __restrict__ z3,
                                                 const float* __restrict__ a1,
                                                 const float* __restrict__ a2,
                                                 const float* __restrict__ b3,
                                                 float* __restrict__ out,
                                                 float* __restrict__ s3,
                                                 float* __restrict__ g2,
                                                 float* __restrict__ g1) {
    int i = blockIdx.x * 256 + threadIdx.x;
    float z3v = z3[i];
    float o = z3v + b3[i];
    out[i] = o;
    s3[i] = o / (z3v + 1e-9f * sgnf(z3v));
    float z2v = z2[i];
    g2[i] = a2[i] / (z2v + 1e-9f * sgnf(z2v));
    float z1v = z1[i];
    g1[i] = a1[i] / (z1v + 1e-9f * sgnf(z1v));
}

// ================= pre-split B planes (blocked, 128-col blocks, 16x16 frag order) ====
// plane element: B^T[col = bi*128 + m*16 + r][k = kt*32 + g*8 + j]
// at index ((bi*128 + kt)*512 + m*64 + g*16 + r)*8 + j
__global__ __launch_bounds__(256) void prepBT(const float* __restrict__ W,
                                              ushort* __restrict__ Ph,
                                              ushort* __restrict__ Pm,
                                              ushort* __restrict__ Pl) {
    size_t ci = (size_t)blockIdx.x * 256 + threadIdx.x;
    int r = (int)(ci & 15);
    int g = (int)((ci >> 4) & 3);
    int m = (int)((ci >> 6) & 7);
    int kt = (int)((ci >> 9) & 127);
    int bi = (int)(ci >> 16);
    int col = bi * 128 + m * 16 + r;
    int k0 = kt * 32 + g * 8;
    float v[8];
#pragma unroll
    for (int j = 0; j < 8; j++) v[j] = W[(size_t)(k0 + j) * D + col];
    uint hp[4], mp[4], lp[4];
#pragma unroll
    for (int j = 0; j < 4; j++) split3_pk(v[2 * j], v[2 * j + 1], hp[j], mp[j], lp[j]);
    size_t dst = ci * 8;
    uint4 u;
    u.x = hp[0]; u.y = hp[1]; u.z = hp[2]; u.w = hp[3]; *(uint4*)(Ph + dst) = u;
    u.x = mp[0]; u.y = mp[1]; u.z = mp[2]; u.w = mp[3]; *(uint4*)(Pm + dst) = u;
    u.x = lp[0]; u.y = lp[1]; u.z = lp[2]; u.w = lp[3]; *(uint4*)(Pl + dst) = u;
}

// gemm_bs v3: A fp32 split in-kernel cooperatively (cvt_pk), B pre-split planes.
// NEW STRUCTURE: all 24 A/B fragments read to REGISTERS at phase start, barrier
// frees both LDS regions, then SPLITA(next)/LOADA/DMAB issue BEFORE the pure-reg
// 96-MFMA phase (latency hidden under MFMA). Counted vmcnt(6).
// MODE 0: fp32 O.  MODE 1: write O as 3 blocked bf16 planes.
template <int SCALED, int MODE>
__global__ __launch_bounds__(256, 2) void gemm_bs(const float* __restrict__ A,
                                                  const ushort* __restrict__ Bh,
                                                  const ushort* __restrict__ Bm_,
                                                  const ushort* __restrict__ Bl_,
                                                  const float* __restrict__ rs,
                                                  const float* __restrict__ ks,
                                                  const float* __restrict__ cs,
                                                  float* __restrict__ O,
                                                  ushort* __restrict__ Cph,
                                                  ushort* __restrict__ Cpm,
                                                  ushort* __restrict__ Cpl_) {
    __shared__ ushort ldsA[3][4096];
    __shared__ ushort ldsB[2][3][4096];
    int t = threadIdx.x;
    int lane = t & 63, wv = t >> 6;
    int wr = wv >> 1, wc = wv & 1;
    int r = lane & 15, g = lane >> 4;
    int bx = blockIdx.x, by = blockIdx.y;
    size_t row0 = (size_t)by * 128, col0 = (size_t)bx * 128;

    int rr = t >> 1;
    int kh = t & 1;
    int cellb0 = ((rr >> 4) * 64 + (kh * 2 + 0) * 16 + (rr & 15)) * 8;
    int cellb1 = ((rr >> 4) * 64 + (kh * 2 + 1) * 16 + (rr & 15)) * 8;

    f32x4 acc[4][4];
#pragma unroll
    for (int m = 0; m < 4; m++)
#pragma unroll
        for (int n = 0; n < 4; n++) acc[m][n] = (f32x4){0.f, 0.f, 0.f, 0.f};

    float rsv = SCALED ? rs[row0 + rr] : 0.f;
    const float* arow = A + (row0 + rr) * (size_t)D;

    float av[16];
    auto LOADA = [&](int k0) {
        const float4* pa = (const float4*)(arow + k0 + kh * 16);
#pragma unroll
        for (int qq = 0; qq < 4; qq++) {
            float4 w = pa[qq];
            av[qq * 4 + 0] = w.x; av[qq * 4 + 1] = w.y;
            av[qq * 4 + 2] = w.z; av[qq * 4 + 3] = w.w;
        }
        if (SCALED) {
            const float4* pk = (const float4*)(ks + k0 + kh * 16);
#pragma unroll
            for (int qq = 0; qq < 4; qq++) {
                float4 kk = pk[qq];
                av[qq * 4 + 0] *= rsv * kk.x; av[qq * 4 + 1] *= rsv * kk.y;
                av[qq * 4 + 2] *= rsv * kk.z; av[qq * 4 + 3] *= rsv * kk.w;
            }
        }
    };

    auto DMAB = [&](int kt, int buf) {
        size_t bt = ((size_t)bx * 128 + kt) * 4096;
        const ushort* bsrc[3] = {Bh + bt, Bm_ + bt, Bl_ + bt};
#pragma unroll
        for (int p = 0; p < 3; p++) {
            __builtin_amdgcn_global_load_lds(
                (const __attribute__((address_space(1))) uint32_t*)(bsrc[p] + (size_t)t * 8),
                (__attribute__((address_space(3))) uint32_t*)(&ldsB[buf][p][t * 8]), 16, 0, 0);
            __builtin_amdgcn_global_load_lds(
                (const __attribute__((address_space(1))) uint32_t*)(bsrc[p] + (size_t)(t + 256) * 8),
                (__attribute__((address_space(3))) uint32_t*)(&ldsB[buf][p][(t + 256) * 8]), 16, 0, 0);
        }
    };

    auto SPLITA = [&]() {
        uint hp[8], mp[8], lp[8];
#pragma unroll
        for (int j = 0; j < 8; j++) split3_pk(av[2 * j], av[2 * j + 1], hp[j], mp[j], lp[j]);
        uint4 u;
        u.x = hp[0]; u.y = hp[1]; u.z = hp[2]; u.w = hp[3]; *(uint4*)&ldsA[0][cellb0] = u;
        u.x = hp[4]; u.y = hp[5]; u.z = hp[6]; u.w = hp[7]; *(uint4*)&ldsA[0][cellb1] = u;
        u.x = mp[0]; u.y = mp[1]; u.z = mp[2]; u.w = mp[3]; *(uint4*)&ldsA[1][cellb0] = u;
        u.x = mp[4]; u.y = mp[5]; u.z = mp[6]; u.w = mp[7]; *(uint4*)&ldsA[1][cellb1] = u;
        u.x = lp[0]; u.y = lp[1]; u.z = lp[2]; u.w = lp[3]; *(uint4*)&ldsA[2][cellb0] = u;
        u.x = lp[4]; u.y = lp[5]; u.z = lp[6]; u.w = lp[7]; *(uint4*)&ldsA[2][cellb1] = u;
    };

    bf16x8 afr[3][4], bfr[3][4];
    auto READFRAGS = [&](int buf) {
#pragma unroll
        for (int p = 0; p < 3; p++)
#pragma unroll
            for (int m = 0; m < 4; m++)
                afr[p][m] = *(const bf16x8*)&ldsA[p][(wr * 4 + m) * 512 + lane * 8];
#pragma unroll
        for (int p = 0; p < 3; p++)
#pragma unroll
            for (int n = 0; n < 4; n++)
                bfr[p][n] = *(const bf16x8*)&ldsB[buf][p][(wc * 4 + n) * 512 + lane * 8];
    };

    auto MFMA_REG = [&]() {
#pragma unroll
        for (int m = 0; m < 4; m++)
#pragma unroll
            for (int n = 0; n < 4; n++) {
                acc[m][n] = MFMA16(afr[0][m], bfr[0][n], acc[m][n], 0, 0, 0);
                acc[m][n] = MFMA16(afr[0][m], bfr[1][n], acc[m][n], 0, 0, 0);
                acc[m][n] = MFMA16(afr[1][m], bfr[0][n], acc[m][n], 0, 0, 0);
                acc[m][n] = MFMA16(afr[1][m], bfr[1][n], acc[m][n], 0, 0, 0);
                acc[m][n] = MFMA16(afr[0][m], bfr[2][n], acc[m][n], 0, 0, 0);
                acc[m][n] = MFMA16(afr[2][m], bfr[0][n], acc[m][n], 0, 0, 0);
            }
    };

    const int NT = D / 32;

    // prologue: ldsA = tile0; av = tile1 raw; B tiles 0,1 in flight
    LOADA(0);
    SPLITA();
    LOADA(32);
    DMAB(0, 0);
    DMAB(1, 1);
    asm volatile("s_waitcnt vmcnt(6) lgkmcnt(0)" ::: "memory");  // retire LOADA(1)+DMAB(0)
    __builtin_amdgcn_sched_barrier(0);
    __builtin_amdgcn_s_barrier();
    __builtin_amdgcn_sched_barrier(0);

    for (int tt = 0; tt < NT; ++tt) {
        READFRAGS(tt & 1);  // 24 ds_read -> regs
        if (tt < NT - 1) {
            asm volatile("s_waitcnt lgkmcnt(0)" ::: "memory");
            __builtin_amdgcn_sched_barrier(0);
            __builtin_amdgcn_s_barrier();  // ldsA + ldsB[tt&1] free
            __builtin_amdgcn_sched_barrier(0);
            SPLITA();  // ldsA <- tile tt+1 (from av)
            if (tt < NT - 2) {
                LOADA((tt + 2) * 32);  // av <- tile tt+2 raw
                DMAB(tt + 2, tt & 1);  // freed B buffer
            }
        }
        MFMA_REG();  // pure-register MFMA; async work flies underneath
        if (tt < NT - 1) {
            if (tt < NT - 2)
                asm volatile("s_waitcnt vmcnt(6) lgkmcnt(0)" ::: "memory");
            else
                asm volatile("s_waitcnt vmcnt(0) lgkmcnt(0)" ::: "memory");
            __builtin_amdgcn_sched_barrier(0);
            __builtin_amdgcn_s_barrier();
            __builtin_amdgcn_sched_barrier(0);
        }
    }

    float csv[4];
#pragma unroll
    for (int n = 0; n < 4; n++) csv[n] = cs[col0 + wc * 64 + n * 16 + r];
#pragma unroll
    for (int m = 0; m < 4; m++)
#pragma unroll
        for (int n = 0; n < 4; n++) {
            if (MODE == 0) {
#pragma unroll
                for (int j = 0; j < 4; j++) {
                    size_t grow = row0 + wr * 64 + m * 16 + g * 4 + j;
                    size_t gcol = col0 + wc * 64 + n * 16 + r;
                    O[grow * D + gcol] = acc[m][n][j] * csv[n];
                }
            } else {
                float v0 = acc[m][n][0] * csv[n], v1 = acc[m][n][1] * csv[n];
                float v2 = acc[m][n][2] * csv[n], v3 = acc[m][n][3] * csv[n];
                uint hp0, mp0, lp0, hp1, mp1, lp1;
                split3_pk(v0, v1, hp0, mp0, lp0);
                split3_pk(v2, v3, hp1, mp1, lp1);
                int k = (int)(col0 + wc * 64 + n * 16 + r);
                int kt = k >> 5, gg = (k & 31) >> 3, jj = k & 7;
#pragma unroll
                for (int j = 0; j < 4; j++) {
                    int i = (int)(row0 + wr * 64 + m * 16 + g * 4 + j);
                    int bi = i >> 7, mm = (i & 127) >> 4, ri = i & 15;
                    size_t off = ((size_t)bi * 128 + kt) * 4096 +
                                 (size_t)(mm * 64 + gg * 16 + ri) * 8 + jj;
                    uint hpk = (j < 2) ? hp0 : hp1;
                    uint mpk = (j < 2) ? mp0 : mp1;
                    uint lpk = (j < 2) ? lp0 : lp1;
                    int sh = (j & 1) * 16;
                    Cph[off] = (ushort)(hpk >> sh);
                    Cpm[off] = (ushort)(mpk >> sh);
                    Cpl_[off] = (ushort)(lpk >> sh);
                }
            }
        }
}

// gemm_ab2 v3: both operands pre-split planes, all-DMA. Frag reads to regs,
// barrier frees LDS, DMAA(tt+1)+DMAB(tt+2) issue BEFORE pure-reg MFMA phase.
// ldsA single (24 KB) + ldsB double (48 KB) = 72 KB -> 2 blocks/CU.
__global__ __launch_bounds__(256, 2) void gemm_ab2(const ushort* __restrict__ Ah,
                                                   const ushort* __restrict__ Am_,
                                                   const ushort* __restrict__ Al_,
                                                   const ushort* __restrict__ Bh,
                                                   const ushort* __restrict__ Bm_,
                                                   const ushort* __restrict__ Bl_,
                                                   const float* __restrict__ cs,
                                                   float* __restrict__ O) {
    __shared__ ushort ldsA[3][4096];
    __shared__ ushort ldsB[2][3][4096];
    int t = threadIdx.x;
    int lane = t & 63, wv = t >> 6;
    int wr = wv >> 1, wc = wv & 1;
    int r = lane & 15, g = lane >> 4;
    int bx = blockIdx.x, by = blockIdx.y;
    size_t row0 = (size_t)by * 128, col0 = (size_t)bx * 128;

    f32x4 acc[4][4];
#pragma unroll
    for (int m = 0; m < 4; m++)
#pragma unroll
        for (int n = 0; n < 4; n++) acc[m][n] = (f32x4){0.f, 0.f, 0.f, 0.f};

    auto DMAA = [&](int kt) {
        size_t at = ((size_t)by * 128 + kt) * 4096;
        const ushort* asrc[3] = {Ah + at, Am_ + at, Al_ + at};
#pragma unroll
        for (int p = 0; p < 3; p++) {
            __builtin_amdgcn_global_load_lds(
                (const __attribute__((address_space(1))) uint32_t*)(asrc[p] + (size_t)t * 8),
                (__attribute__((address_space(3))) uint32_t*)(&ldsA[p][t * 8]), 16, 0, 0);
            __builtin_amdgcn_global_load_lds(
                (const __attribute__((address_space(1))) uint32_t*)(asrc[p] + (size_t)(t + 256) * 8),
                (__attribute__((address_space(3))) uint32_t*)(&ldsA[p][(t + 256) * 8]), 16, 0, 0);
        }
    };

    auto DMAB = [&](int kt, int buf) {
        size_t bt = ((size_t)bx * 128 + kt) * 4096;
        const ushort* bsrc[3] = {Bh + bt, Bm_ + bt, Bl_ + bt};
#pragma unroll
        for (int p = 0; p < 3; p++) {
            __builtin_amdgcn_global_load_lds(
                (const __attribute__((address_space(1))) uint32_t*)(bsrc[p] + (size_t)t * 8),
                (__attribute__((address_space(3))) uint32_t*)(&ldsB[buf][p][t * 8]), 16, 0, 0);
            __builtin_amdgcn_global_load_lds(
                (const __attribute__((address_space(1))) uint32_t*)(bsrc[p] + (size_t)(t + 256) * 8),
                (__attribute__((address_space(3))) uint32_t*)(&ldsB[buf][p][(t + 256) * 8]), 16, 0, 0);
        }
    };

    bf16x8 afr[3][4], bfr[3][4];
    auto READFRAGS = [&](int buf) {
#pragma unroll
        for (int p = 0; p < 3; p++)
#pragma unroll
            for (int m = 0; m < 4; m++)
                afr[p][m] = *(const bf16x8*)&ldsA[p][(wr * 4 + m) * 512 + lane * 8];
#pragma unroll
        for (int p = 0; p < 3; p++)
#pragma unroll
            for (int n = 0; n < 4; n++)
                bfr[p][n] = *(const bf16x8*)&ldsB[buf][p][(wc * 4 + n) * 512 + lane * 8];
    };

    auto MFMA_REG = [&]() {
#pragma unroll
        for (int m = 0; m < 4; m++)
#pragma unroll
            for (int n = 0; n < 4; n++) {
                acc[m][n] = MFMA16(afr[0][m], bfr[0][n], acc[m][n], 0, 0, 0);
                acc[m][n] = MFMA16(afr[0][m], bfr[1][n], acc[m][n], 0, 0, 0);
                acc[m][n] = MFMA16(afr[1][m], bfr[0][n], acc[m][n], 0, 0, 0);
                acc[m][n] = MFMA16(afr[1][m], bfr[1][n], acc[m][n], 0, 0, 0);
                acc[m][n] = MFMA16(afr[0][m], bfr[2][n], acc[m][n], 0, 0, 0);
                acc[m][n] = MFMA16(afr[2][m], bfr[0][n], acc[m][n], 0, 0, 0);
            }
    };

    const int NT = D / 32;

    DMAA(0);
    DMAB(0, 0);
    DMAB(1, 1);
    asm volatile("s_waitcnt vmcnt(6)" ::: "memory");  // A0 + B0 done, B1 in flight
    __builtin_amdgcn_sched_barrier(0);
    __builtin_amdgcn_s_barrier();
    __builtin_amdgcn_sched_barrier(0);

    for (int tt = 0; tt < NT; ++tt) {
        READFRAGS(tt & 1);
        if (tt < NT - 1) {
            asm volatile("s_waitcnt lgkmcnt(0)" ::: "memory");
            __builtin_amdgcn_sched_barrier(0);
            __builtin_amdgcn_s_barrier();  // ldsA + ldsB[tt&1] free
            __builtin_amdgcn_sched_barrier(0);
            DMAA(tt + 1);
            if (tt < NT - 2) DMAB(tt + 2, tt & 1);
        }
        MFMA_REG();
        if (tt < NT - 1) {
            if (tt < NT - 2)
                asm volatile("s_waitcnt vmcnt(6)" ::: "memory");  // retire B(tt+1)+A(tt+1)
            else
                asm volatile("s_waitcnt vmcnt(0)" ::: "memory");
            __builtin_amdgcn_sched_barrier(0);
            __builtin_amdgcn_s_barrier();
            __builtin_amdgcn_sched_barrier(0);
        }
    }

    float csv[4];
#pragma unroll
    for (int n = 0; n < 4; n++) csv[n] = cs[col0 + wc * 64 + n * 16 + r];
#pragma unroll
    for (int m = 0; m < 4; m++)
#pragma unroll
        for (int n = 0; n < 4; n++)
#pragma unroll
            for (int j = 0; j < 4; j++) {
                size_t grow = row0 + wr * 64 + m * 16 + g * 4 + j;
                size_t gcol = col0 + wc * 64 + n * 16 + r;
                O[grow * D + gcol] = acc[m][n][j] * csv[n];
            }
}

// ================= small-ws fallback (R5-proven) =================
constexpr int BM = 128, BN = 128, LDK = 40;

template <int SCALED>
__global__ __launch_bounds__(256, 2) void gemm3(const float* __restrict__ A,
                                                const float* __restrict__ B,
                                                const float* __restrict__ rs,
                                                const float* __restrict__ ks,
                                                const float* __restrict__ cs,
                                                float* __restrict__ O) {
    __shared__ ushort Ahs[BM][LDK], Ams[BM][LDK], Als[BM][LDK];
    __shared__ ushort Bhs[BN][LDK], Bms[BN][LDK], Bls[BN][LDK];
    int t = threadIdx.x;
    int lane = t & 63, wv = t >> 6;
    int wr = wv >> 1, wc = wv & 1;
    int r = lane & 15, g = lane >> 4;
    size_t row0 = (size_t)blockIdx.y * BM;
    size_t col0 = (size_t)blockIdx.x * BN;
    int sArow = t >> 1, sAk = (t & 1) * 16, sBcol = t & 127, sBk = (t >> 7) * 16;

    f32x4 acc[4][4];
#pragma unroll
    for (int m = 0; m < 4; m++)
#pragma unroll
        for (int n = 0; n < 4; n++) acc[m][n] = (f32x4){0.f, 0.f, 0.f, 0.f};

    float av[16], bv[16];
    auto LOADT = [&](int k0) {
        const float4* pa = (const float4*)(A + (row0 + sArow) * (size_t)D + k0 + sAk);
#pragma unroll
        for (int qq = 0; qq < 4; qq++) {
            float4 w = pa[qq];
            av[qq * 4 + 0] = w.x; av[qq * 4 + 1] = w.y; av[qq * 4 + 2] = w.z; av[qq * 4 + 3] = w.w;
        }
        if (SCALED) {
            float rsv = rs[row0 + sArow];
            const float4* pk = (const float4*)(ks + k0 + sAk);
#pragma unroll
            for (int qq = 0; qq < 4; qq++) {
                float4 kk = pk[qq];
                av[qq * 4 + 0] *= rsv * kk.x; av[qq * 4 + 1] *= rsv * kk.y;
                av[qq * 4 + 2] *= rsv * kk.z; av[qq * 4 + 3] *= rsv * kk.w;
            }
        }
        const float* pb = B + ((size_t)k0 + sBk) * D + col0 + sBcol;
#pragma unroll
        for (int kk = 0; kk < 16; kk++) bv[kk] = pb[(size_t)kk * D];
    };

    LOADT(0);
    for (int kt = 0; kt < D / 32; ++kt) {
        __syncthreads();
        {
            uint hp[8], mp[8], lp[8];
#pragma unroll
            for (int j = 0; j < 8; j++) split3_pk(av[2 * j], av[2 * j + 1], hp[j], mp[j], lp[j]);
            uint4 u;
            u.x = hp[0]; u.y = hp[1]; u.z = hp[2]; u.w = hp[3]; *(uint4*)&Ahs[sArow][sAk] = u;
            u.x = hp[4]; u.y = hp[5]; u.z = hp[6]; u.w = hp[7]; *(uint4*)&Ahs[sArow][sAk + 8] = u;
            u.x = mp[0]; u.y = mp[1]; u.z = mp[2]; u.w = mp[3]; *(uint4*)&Ams[sArow][sAk] = u;
            u.x = mp[4]; u.y = mp[5]; u.z = mp[6]; u.w = mp[7]; *(uint4*)&Ams[sArow][sAk + 8] = u;
            u.x = lp[0]; u.y = lp[1]; u.z = lp[2]; u.w = lp[3]; *(uint4*)&Als[sArow][sAk] = u;
            u.x = lp[4]; u.y = lp[5]; u.z = lp[6]; u.w = lp[7]; *(uint4*)&Als[sArow][sAk + 8] = u;
        }
        {
            uint hp[8], mp[8], lp[8];
#pragma unroll
            for (int j = 0; j < 8; j++) split3_pk(bv[2 * j], bv[2 * j + 1], hp[j], mp[j], lp[j]);
            uint4 u;
            u.x = hp[0]; u.y = hp[1]; u.z = hp[2]; u.w = hp[3]; *(uint4*)&Bhs[sBcol][sBk] = u;
            u.x = hp[4]; u.y = hp[5]; u.z = hp[6]; u.w = hp[7]; *(uint4*)&Bhs[sBcol][sBk + 8] = u;
            u.x = mp[0]; u.y = mp[1]; u.z = mp[2]; u.w = mp[3]; *(uint4*)&Bms[sBcol][sBk] = u;
            u.x = mp[4]; u.y = mp[5]; u.z = mp[6]; u.w = mp[7]; *(uint4*)&Bms[sBcol][sBk + 8] = u;
            u.x = lp[0]; u.y = lp[1]; u.z = lp[2]; u.w = lp[3]; *(uint4*)&Bls[sBcol][sBk] = u;
            u.x = lp[4]; u.y = lp[5]; u.z = lp[6]; u.w = lp[7]; *(uint4*)&Bls[sBcol][sBk + 8] = u;
        }
        __syncthreads();
        if (kt + 1 < D / 32) LOADT((kt + 1) * 32);

        bf16x8 bh[4], bm[4], bl[4];
#pragma unroll
        for (int n = 0; n < 4; n++) {
            bh[n] = *(const bf16x8*)&Bhs[wc * 64 + n * 16 + r][g * 8];
            bm[n] = *(const bf16x8*)&Bms[wc * 64 + n * 16 + r][g * 8];
            bl[n] = *(const bf16x8*)&Bls[wc * 64 + n * 16 + r][g * 8];
        }
#pragma unroll
        for (int m = 0; m < 4; m++) {
            bf16x8 ah = *(const bf16x8*)&Ahs[wr * 64 + m * 16 + r][g * 8];
            bf16x8 am = *(const bf16x8*)&Ams[wr * 64 + m * 16 + r][g * 8];
            bf16x8 al = *(const bf16x8*)&Als[wr * 64 + m * 16 + r][g * 8];
#pragma unroll
            for (int n = 0; n < 4; n++) {
                acc[m][n] = MFMA16(ah, bh[n], acc[m][n], 0, 0, 0);
                acc[m][n] = MFMA16(ah, bm[n], acc[m][n], 0, 0, 0);
                acc[m][n] = MFMA16(am, bh[n], acc[m][n], 0, 0, 0);
                acc[m][n] = MFMA16(am, bm[n], acc[m][n], 0, 0, 0);
                acc[m][n] = MFMA16(ah, bl[n], acc[m][n], 0, 0, 0);
                acc[m][n] = MFMA16(al, bh[n], acc[m][n], 0, 0, 0);
            }
        }
    }
    float csv[4];
#pragma unroll
    for (int n = 0; n < 4; n++) csv[n] = cs[col0 + wc * 64 + n * 16 + r];
#pragma unroll
    for (int m = 0; m < 4; m++)
#pragma unroll
        for (int n = 0; n < 4; n++)
#pragma unroll
            for (int j = 0; j < 4; j++) {
                size_t grow = row0 + wr * 64 + m * 16 + g * 4 + j;
                size_t gcol = col0 + wc * 64 + n * 16 + r;
                O[grow * D + gcol] = acc[m][n][j] * csv[n];
            }
}

extern "C" void kernel_launch(void* const* d_in, const int* in_sizes, int n_in,
                              void* d_out, int out_size, void* d_ws, size_t ws_size,
                              hipStream_t stream) {
    const float* x = (const float*)d_in[0];
    const float* W1 = (const float*)d_in[1];
    const float* b1 = (const float*)d_in[2];
    const float* W2 = (const float*)d_in[3];
    const float* b2 = (const float*)d_in[4];
    const float* W3 = (const float*)d_in[5];
    const float* b3 = (const float*)d_in[6];

    float* out = (float*)d_out;
    float* Rout = out + D;

    char* ws = (char*)d_ws;
    float* z1 = (float*)ws;
    float* z2 = z1 + D;
    float* z3 = z2 + D;
    float* a1 = z3 + D;
    float* a2 = a1 + D;
    float* s3 = a2 + D;
    float* g2 = s3 + D;
    float* g1 = g2 + D;
    size_t smallB = (size_t)D * 8 * sizeof(float);

    const size_t PL = (size_t)D * D;                     // ushorts per plane (32 MB)
    size_t planesB = 3 * PL * sizeof(ushort);            // 96 MB
    size_t cB = (size_t)D * D * sizeof(float);           // 64 MB
    size_t need2 = smallB + 2 * planesB + 256;           // ~192.13 MB (proven available)
    size_t need1 = smallB + planesB + cB + 256;          // ~160.13 MB

    // forward pass — bit-exact numpy-f32 emulation (unchanged)
    gemv_blas8<<<(D * 8) / 256, 256, 0, stream>>>(W1, x, b1, z1, a1, 1);
    gemv_blas8<<<(D * 8) / 256, 256, 0, stream>>>(W2, a1, b2, z2, a2, 1);
    gemv_blas8<<<(D * 8) / 256, 256, 0, stream>>>(W3, a2, b3, z3, nullptr, 0);
    vecprep32<<<D / 256, 256, 0, stream>>>(z1, z2, z3, a1, a2, b3, out, s3, g2, g1);

    dim3 gg(D / 128, D / 128);
    int pgrid = (int)((PL / 8) / 256);
    if (ws_size >= need2) {
        ushort* Bpl = (ushort*)(ws + smallB);
        ushort* Cpl = Bpl + 3 * PL;
        prepBT<<<pgrid, 256, 0, stream>>>(W2, Bpl, Bpl + PL, Bpl + 2 * PL);
        gemm_bs<1, 1><<<gg, 256, 0, stream>>>(W3, Bpl, Bpl + PL, Bpl + 2 * PL,
                                              s3, g2, g1, nullptr,
                                              Cpl, Cpl + PL, Cpl + 2 * PL);
        prepBT<<<pgrid, 256, 0, stream>>>(W1, Bpl, Bpl + PL, Bpl + 2 * PL);
        gemm_ab2<<<gg, 256, 0, stream>>>(Cpl, Cpl + PL, Cpl + 2 * PL,
                                         Bpl, Bpl + PL, Bpl + 2 * PL, x, Rout);
    } else if (ws_size >= need1) {
        ushort* Bpl = (ushort*)(ws + smallB);
        float* C = (float*)(ws + smallB + planesB);
        prepBT<<<pgrid, 256, 0, stream>>>(W2, Bpl, Bpl + PL, Bpl + 2 * PL);
        gemm_bs<1, 0><<<gg, 256, 0, stream>>>(W3, Bpl, Bpl + PL, Bpl + 2 * PL,
                                              s3, g2, g1, C, nullptr, nullptr, nullptr);
        prepBT<<<pgrid, 256, 0, stream>>>(W1, Bpl, Bpl + PL, Bpl + 2 * PL);
        gemm_bs<0, 0><<<gg, 256, 0, stream>>>(C, Bpl, Bpl + PL, Bpl + 2 * PL,
                                              nullptr, nullptr, x, Rout, nullptr, nullptr, nullptr);
    } else {
        float* C = (float*)(ws + smallB);
        gemm3<1><<<gg, 256, 0, stream>>>(W3, W2, s3, g2, g1, C);
        gemm3<0><<<gg, 256, 0, stream>>>(C, W1, nullptr, nullptr, x, Rout);
    }
}

// Round 17
// 1590.663 us; speedup vs baseline: 1.1444x; 1.0313x over previous
//
#include <hip/hip_runtime.h>
#include <stdint.h>

#define D 4096

typedef __attribute__((ext_vector_type(8))) short bf16x8;
typedef __attribute__((ext_vector_type(4))) float f32x4;

#define MFMA16 __builtin_amdgcn_mfma_f32_16x16x32_bf16

__device__ __forceinline__ float sgnf(float z) {
    return (z > 0.f) ? 1.f : ((z < 0.f) ? -1.f : 0.f);
}

// HW pair convert+pack: dst = { lo16: bf16(a), hi16: bf16(b) }  (gfx950)
__device__ __forceinline__ uint cvtpk(float a, float b) {
    uint r;
    asm("v_cvt_pk_bf16_f32 %0, %1, %2" : "=v"(r) : "v"(a), "v"(b));
    return r;
}
// triple-split a pair of fp32 into packed h/m/l bf16 pairs (exact residuals).
__device__ __forceinline__ void split3_pk(float f0, float f1, uint& hp, uint& mp, uint& lp) {
    hp = cvtpk(f0, f1);
    float h0 = __uint_as_float(hp << 16);
    float h1 = __uint_as_float(hp & 0xffff0000u);
    float r0 = f0 - h0, r1 = f1 - h1;
    mp = cvtpk(r0, r1);
    float m0 = __uint_as_float(mp << 16);
    float m1 = __uint_as_float(mp & 0xffff0000u);
    lp = cvtpk(r0 - m0, r1 - m1);
}

// ---- forward GEMV: bit-exact emulation of numpy-f32 (OpenBLAS AVX2 sgemv_t) ----
// DO NOT TOUCH — bit-exactness of z1/z2/z3 vs the reference is load-bearing.
__global__ __launch_bounds__(256) void gemv_blas8(const float* __restrict__ W,
                                                  const float* __restrict__ v,
                                                  const float* __restrict__ bias,
                                                  float* __restrict__ z,
                                                  float* __restrict__ act, int doAct) {
    int gid = blockIdx.x * 256 + threadIdx.x;
    int row = gid >> 3;
    int l = gid & 7;
    const float* wr = W + (size_t)row * D;
    float acc = 0.f;
    for (int k = l; k < D; k += 8) acc = fmaf(wr[k], v[k], acc);
    float b = acc + __shfl_xor(acc, 4);
    float c = b + __shfl_xor(b, 1);
    float s = c + __shfl_xor(c, 2);
    if (l == 0) {
        z[row] = s;
        if (doAct) act[row] = fmaxf(s + bias[row], 0.f);
    }
}

__global__ __launch_bounds__(256) void vecprep32(const float* __restrict__ z1,
                                                 const float* __restrict__ z2,
                                                 const float* __restrict__ z3,
                                                 const float* __restrict__ a1,
                                                 const float* __restrict__ a2,
                                                 const float* __restrict__ b3,
                                                 float* __restrict__ out,
                                                 float* __restrict__ s3,
                                                 float* __restrict__ g2,
                                                 float* __restrict__ g1) {
    int i = blockIdx.x * 256 + threadIdx.x;
    float z3v = z3[i];
    float o = z3v + b3[i];
    out[i] = o;
    s3[i] = o / (z3v + 1e-9f * sgnf(z3v));
    float z2v = z2[i];
    g2[i] = a2[i] / (z2v + 1e-9f * sgnf(z2v));
    float z1v = z1[i];
    g1[i] = a1[i] / (z1v + 1e-9f * sgnf(z1v));
}

// ================= pre-split B planes (blocked, 128-col blocks) =================
// plane element: B^T[col = bi*128 + m*16 + r][k = kt*32 + g*8 + j]
// at index ((bi*128 + kt)*512 + m*64 + g*16 + r)*8 + j
__global__ __launch_bounds__(256) void prepBT(const float* __restrict__ W,
                                              ushort* __restrict__ Ph,
                                              ushort* __restrict__ Pm,
                                              ushort* __restrict__ Pl) {
    size_t ci = (size_t)blockIdx.x * 256 + threadIdx.x;
    int r = (int)(ci & 15);
    int g = (int)((ci >> 4) & 3);
    int m = (int)((ci >> 6) & 7);
    int kt = (int)((ci >> 9) & 127);
    int bi = (int)(ci >> 16);
    int col = bi * 128 + m * 16 + r;
    int k0 = kt * 32 + g * 8;
    float v[8];
#pragma unroll
    for (int j = 0; j < 8; j++) v[j] = W[(size_t)(k0 + j) * D + col];
    uint hp[4], mp[4], lp[4];
#pragma unroll
    for (int j = 0; j < 4; j++) split3_pk(v[2 * j], v[2 * j + 1], hp[j], mp[j], lp[j]);
    size_t dst = ci * 8;
    uint4 u;
    u.x = hp[0]; u.y = hp[1]; u.z = hp[2]; u.w = hp[3]; *(uint4*)(Ph + dst) = u;
    u.x = mp[0]; u.y = mp[1]; u.z = mp[2]; u.w = mp[3]; *(uint4*)(Pm + dst) = u;
    u.x = lp[0]; u.y = lp[1]; u.z = lp[2]; u.w = lp[3]; *(uint4*)(Pl + dst) = u;
}

// gemm_bs: O[i,c] = (Sum_k Asc[i,k]*B[k,c]) * cs[c]; A fp32 split in-kernel
// cooperatively (cvt_pk), B pre-split blocked planes, DMA-staged double-buffered
// with counted vmcnt (R8/R12-proven). 6 products: hh+hm+mh+mm+hl+lh.
// MODE 0: fp32 O.  MODE 1: write O as 3 blocked bf16 planes (256-row-block layout).
template <int SCALED, int MODE>
__global__ __launch_bounds__(256, 2) void gemm_bs(const float* __restrict__ A,
                                                  const ushort* __restrict__ Bh,
                                                  const ushort* __restrict__ Bm_,
                                                  const ushort* __restrict__ Bl_,
                                                  const float* __restrict__ rs,
                                                  const float* __restrict__ ks,
                                                  const float* __restrict__ cs,
                                                  float* __restrict__ O,
                                                  ushort* __restrict__ Cph,
                                                  ushort* __restrict__ Cpm,
                                                  ushort* __restrict__ Cpl_) {
    __shared__ ushort ldsA[3][4096];
    __shared__ ushort ldsB[2][3][4096];
    int t = threadIdx.x;
    int lane = t & 63, wv = t >> 6;
    int wr = wv >> 1, wc = wv & 1;
    int r = lane & 15, g = lane >> 4;
    int bx = blockIdx.x, by = blockIdx.y;
    size_t row0 = (size_t)by * 128, col0 = (size_t)bx * 128;

    int rr = t >> 1;
    int kh = t & 1;
    int cellb0 = ((rr >> 4) * 64 + (kh * 2 + 0) * 16 + (rr & 15)) * 8;
    int cellb1 = ((rr >> 4) * 64 + (kh * 2 + 1) * 16 + (rr & 15)) * 8;

    f32x4 acc[4][4];
#pragma unroll
    for (int m = 0; m < 4; m++)
#pragma unroll
        for (int n = 0; n < 4; n++) acc[m][n] = (f32x4){0.f, 0.f, 0.f, 0.f};

    float rsv = SCALED ? rs[row0 + rr] : 0.f;
    const float* arow = A + (row0 + rr) * (size_t)D;

    float av[16];
    auto LOADA = [&](int k0) {
        const float4* pa = (const float4*)(arow + k0 + kh * 16);
#pragma unroll
        for (int qq = 0; qq < 4; qq++) {
            float4 w = pa[qq];
            av[qq * 4 + 0] = w.x; av[qq * 4 + 1] = w.y;
            av[qq * 4 + 2] = w.z; av[qq * 4 + 3] = w.w;
        }
        if (SCALED) {
            const float4* pk = (const float4*)(ks + k0 + kh * 16);
#pragma unroll
            for (int qq = 0; qq < 4; qq++) {
                float4 kk = pk[qq];
                av[qq * 4 + 0] *= rsv * kk.x; av[qq * 4 + 1] *= rsv * kk.y;
                av[qq * 4 + 2] *= rsv * kk.z; av[qq * 4 + 3] *= rsv * kk.w;
            }
        }
    };

    auto DMAB = [&](int kt, int buf) {
        size_t bt = ((size_t)bx * 128 + kt) * 4096;
        const ushort* bsrc[3] = {Bh + bt, Bm_ + bt, Bl_ + bt};
#pragma unroll
        for (int p = 0; p < 3; p++) {
            __builtin_amdgcn_global_load_lds(
                (const __attribute__((address_space(1))) uint32_t*)(bsrc[p] + (size_t)t * 8),
                (__attribute__((address_space(3))) uint32_t*)(&ldsB[buf][p][t * 8]), 16, 0, 0);
            __builtin_amdgcn_global_load_lds(
                (const __attribute__((address_space(1))) uint32_t*)(bsrc[p] + (size_t)(t + 256) * 8),
                (__attribute__((address_space(3))) uint32_t*)(&ldsB[buf][p][(t + 256) * 8]), 16, 0, 0);
        }
    };

    auto SPLITA = [&]() {
        uint hp[8], mp[8], lp[8];
#pragma unroll
        for (int j = 0; j < 8; j++) split3_pk(av[2 * j], av[2 * j + 1], hp[j], mp[j], lp[j]);
        uint4 u;
        u.x = hp[0]; u.y = hp[1]; u.z = hp[2]; u.w = hp[3]; *(uint4*)&ldsA[0][cellb0] = u;
        u.x = hp[4]; u.y = hp[5]; u.z = hp[6]; u.w = hp[7]; *(uint4*)&ldsA[0][cellb1] = u;
        u.x = mp[0]; u.y = mp[1]; u.z = mp[2]; u.w = mp[3]; *(uint4*)&ldsA[1][cellb0] = u;
        u.x = mp[4]; u.y = mp[5]; u.z = mp[6]; u.w = mp[7]; *(uint4*)&ldsA[1][cellb1] = u;
        u.x = lp[0]; u.y = lp[1]; u.z = lp[2]; u.w = lp[3]; *(uint4*)&ldsA[2][cellb0] = u;
        u.x = lp[4]; u.y = lp[5]; u.z = lp[6]; u.w = lp[7]; *(uint4*)&ldsA[2][cellb1] = u;
    };

    auto MFMA_PHASE = [&](int buf) {
        bf16x8 bh[4], bm[4], bl[4];
#pragma unroll
        for (int n = 0; n < 4; n++) bh[n] = *(const bf16x8*)&ldsB[buf][0][(wc * 4 + n) * 512 + lane * 8];
#pragma unroll
        for (int n = 0; n < 4; n++) bm[n] = *(const bf16x8*)&ldsB[buf][1][(wc * 4 + n) * 512 + lane * 8];
#pragma unroll
        for (int n = 0; n < 4; n++) bl[n] = *(const bf16x8*)&ldsB[buf][2][(wc * 4 + n) * 512 + lane * 8];
        {
            bf16x8 a[4];
#pragma unroll
            for (int m = 0; m < 4; m++) a[m] = *(const bf16x8*)&ldsA[0][(wr * 4 + m) * 512 + lane * 8];
#pragma unroll
            for (int m = 0; m < 4; m++)
#pragma unroll
                for (int n = 0; n < 4; n++) {
                    acc[m][n] = MFMA16(a[m], bh[n], acc[m][n], 0, 0, 0);
                    acc[m][n] = MFMA16(a[m], bm[n], acc[m][n], 0, 0, 0);
                    acc[m][n] = MFMA16(a[m], bl[n], acc[m][n], 0, 0, 0);
                }
        }
        {
            bf16x8 a[4];
#pragma unroll
            for (int m = 0; m < 4; m++) a[m] = *(const bf16x8*)&ldsA[1][(wr * 4 + m) * 512 + lane * 8];
#pragma unroll
            for (int m = 0; m < 4; m++)
#pragma unroll
                for (int n = 0; n < 4; n++) {
                    acc[m][n] = MFMA16(a[m], bh[n], acc[m][n], 0, 0, 0);
                    acc[m][n] = MFMA16(a[m], bm[n], acc[m][n], 0, 0, 0);
                }
        }
        {
            bf16x8 a[4];
#pragma unroll
            for (int m = 0; m < 4; m++) a[m] = *(const bf16x8*)&ldsA[2][(wr * 4 + m) * 512 + lane * 8];
#pragma unroll
            for (int m = 0; m < 4; m++)
#pragma unroll
                for (int n = 0; n < 4; n++)
                    acc[m][n] = MFMA16(a[m], bh[n], acc[m][n], 0, 0, 0);
        }
    };

    const int NT = D / 32;

    LOADA(0);
    SPLITA();
    DMAB(0, 0);
    LOADA(32);
    DMAB(1, 1);
    asm volatile("s_waitcnt vmcnt(6) lgkmcnt(0)" ::: "memory");
    __builtin_amdgcn_s_barrier();
    __builtin_amdgcn_sched_barrier(0);

    for (int tt = 0; tt < NT; ++tt) {
        MFMA_PHASE(tt & 1);
        __builtin_amdgcn_sched_barrier(0);
        __builtin_amdgcn_s_barrier();
        __builtin_amdgcn_sched_barrier(0);
        if (tt < NT - 1) {
            SPLITA();
            if (tt < NT - 2) {
                LOADA((tt + 2) * 32);
                DMAB(tt + 2, tt & 1);
                asm volatile("s_waitcnt vmcnt(6) lgkmcnt(0)" ::: "memory");
            } else {
                asm volatile("s_waitcnt vmcnt(0) lgkmcnt(0)" ::: "memory");
            }
            __builtin_amdgcn_s_barrier();
            __builtin_amdgcn_sched_barrier(0);
        }
    }

    float csv[4];
#pragma unroll
    for (int n = 0; n < 4; n++) csv[n] = cs[col0 + wc * 64 + n * 16 + r];
#pragma unroll
    for (int m = 0; m < 4; m++)
#pragma unroll
        for (int n = 0; n < 4; n++) {
            if (MODE == 0) {
#pragma unroll
                for (int j = 0; j < 4; j++) {
                    size_t grow = row0 + wr * 64 + m * 16 + g * 4 + j;
                    size_t gcol = col0 + wc * 64 + n * 16 + r;
                    O[grow * D + gcol] = acc[m][n][j] * csv[n];
                }
            } else {
                float v0 = acc[m][n][0] * csv[n], v1 = acc[m][n][1] * csv[n];
                float v2 = acc[m][n][2] * csv[n], v3 = acc[m][n][3] * csv[n];
                uint hp0, mp0, lp0, hp1, mp1, lp1;
                split3_pk(v0, v1, hp0, mp0, lp0);
                split3_pk(v2, v3, hp1, mp1, lp1);
                int k = (int)(col0 + wc * 64 + n * 16 + r);
                int kt = k >> 5, gg = (k & 31) >> 3, jj = k & 7;
#pragma unroll
                for (int j = 0; j < 4; j++) {
                    int i = (int)(row0 + wr * 64 + m * 16 + g * 4 + j);
                    int bi = i >> 8, mm = (i & 255) >> 4, ri = i & 15;
                    size_t off = ((size_t)bi * 128 + kt) * 8192 +
                                 (size_t)(mm * 64 + gg * 16 + ri) * 8 + jj;
                    uint hpk = (j < 2) ? hp0 : hp1;
                    uint mpk = (j < 2) ? mp0 : mp1;
                    uint lpk = (j < 2) ? lp0 : lp1;
                    int sh = (j & 1) * 16;
                    Cph[off] = (ushort)(hpk >> sh);
                    Cpm[off] = (ushort)(mpk >> sh);
                    Cpl_[off] = (ushort)(lpk >> sh);
                }
            }
        }
}

// gemm_ab2: BOTH operands pre-split blocked planes, all-DMA (zero K-loop VALU),
// 128x128 tile, 256 threads, 4 waves. A single-buffered (24 KB), B double-
// buffered (48 KB) -> 72 KB LDS -> 2 blocks/CU. Counted vmcnt. T5 setprio
// around the MFMA phase (2 co-resident blocks are phase-offset -> role diversity).
// A planes use the 256-row-block layout written by gemm_bs MODE 1: the 128-row
// tile (by,kt) lives at ((by>>1)*128+kt)*8192 + (by&1)*4096, contiguous 4096.
__global__ __launch_bounds__(256, 2) void gemm_ab2(const ushort* __restrict__ Ah,
                                                   const ushort* __restrict__ Am_,
                                                   const ushort* __restrict__ Al_,
                                                   const ushort* __restrict__ Bh,
                                                   const ushort* __restrict__ Bm_,
                                                   const ushort* __restrict__ Bl_,
                                                   const float* __restrict__ cs,
                                                   float* __restrict__ O) {
    __shared__ ushort ldsA[3][4096];     // 24 KB, single buffer
    __shared__ ushort ldsB[2][3][4096];  // 48 KB, double buffer
    int t = threadIdx.x;
    int lane = t & 63, wv = t >> 6;
    int wr = wv >> 1, wc = wv & 1;
    int r = lane & 15, g = lane >> 4;
    int bx = blockIdx.x, by = blockIdx.y;
    size_t row0 = (size_t)by * 128, col0 = (size_t)bx * 128;

    f32x4 acc[4][4];
#pragma unroll
    for (int m = 0; m < 4; m++)
#pragma unroll
        for (int n = 0; n < 4; n++) acc[m][n] = (f32x4){0.f, 0.f, 0.f, 0.f};

    size_t abase = ((size_t)(by >> 1) * 128) * 8192 + (size_t)(by & 1) * 4096;

    auto DMAA = [&](int kt) {
        size_t at = abase + (size_t)kt * 8192;
        const ushort* asrc[3] = {Ah + at, Am_ + at, Al_ + at};
#pragma unroll
        for (int p = 0; p < 3; p++) {
            __builtin_amdgcn_global_load_lds(
                (const __attribute__((address_space(1))) uint32_t*)(asrc[p] + (size_t)t * 8),
                (__attribute__((address_space(3))) uint32_t*)(&ldsA[p][t * 8]), 16, 0, 0);
            __builtin_amdgcn_global_load_lds(
                (const __attribute__((address_space(1))) uint32_t*)(asrc[p] + (size_t)(t + 256) * 8),
                (__attribute__((address_space(3))) uint32_t*)(&ldsA[p][(t + 256) * 8]), 16, 0, 0);
        }
    };

    auto DMAB = [&](int kt, int buf) {
        size_t bt = ((size_t)bx * 128 + kt) * 4096;
        const ushort* bsrc[3] = {Bh + bt, Bm_ + bt, Bl_ + bt};
#pragma unroll
        for (int p = 0; p < 3; p++) {
            __builtin_amdgcn_global_load_lds(
                (const __attribute__((address_space(1))) uint32_t*)(bsrc[p] + (size_t)t * 8),
                (__attribute__((address_space(3))) uint32_t*)(&ldsB[buf][p][t * 8]), 16, 0, 0);
            __builtin_amdgcn_global_load_lds(
                (const __attribute__((address_space(1))) uint32_t*)(bsrc[p] + (size_t)(t + 256) * 8),
                (__attribute__((address_space(3))) uint32_t*)(&ldsB[buf][p][(t + 256) * 8]), 16, 0, 0);
        }
    };

    auto MFMA_PHASE = [&](int buf) {
        __builtin_amdgcn_s_setprio(1);
        bf16x8 bh[4], bm[4], bl[4];
#pragma unroll
        for (int n = 0; n < 4; n++) bh[n] = *(const bf16x8*)&ldsB[buf][0][(wc * 4 + n) * 512 + lane * 8];
#pragma unroll
        for (int n = 0; n < 4; n++) bm[n] = *(const bf16x8*)&ldsB[buf][1][(wc * 4 + n) * 512 + lane * 8];
#pragma unroll
        for (int n = 0; n < 4; n++) bl[n] = *(const bf16x8*)&ldsB[buf][2][(wc * 4 + n) * 512 + lane * 8];
        {
            bf16x8 a[4];
#pragma unroll
            for (int m = 0; m < 4; m++) a[m] = *(const bf16x8*)&ldsA[0][(wr * 4 + m) * 512 + lane * 8];
#pragma unroll
            for (int m = 0; m < 4; m++)
#pragma unroll
                for (int n = 0; n < 4; n++) {
                    acc[m][n] = MFMA16(a[m], bh[n], acc[m][n], 0, 0, 0);
                    acc[m][n] = MFMA16(a[m], bm[n], acc[m][n], 0, 0, 0);
                    acc[m][n] = MFMA16(a[m], bl[n], acc[m][n], 0, 0, 0);
                }
        }
        {
            bf16x8 a[4];
#pragma unroll
            for (int m = 0; m < 4; m++) a[m] = *(const bf16x8*)&ldsA[1][(wr * 4 + m) * 512 + lane * 8];
#pragma unroll
            for (int m = 0; m < 4; m++)
#pragma unroll
                for (int n = 0; n < 4; n++) {
                    acc[m][n] = MFMA16(a[m], bh[n], acc[m][n], 0, 0, 0);
                    acc[m][n] = MFMA16(a[m], bm[n], acc[m][n], 0, 0, 0);
                }
        }
        {
            bf16x8 a[4];
#pragma unroll
            for (int m = 0; m < 4; m++) a[m] = *(const bf16x8*)&ldsA[2][(wr * 4 + m) * 512 + lane * 8];
#pragma unroll
            for (int m = 0; m < 4; m++)
#pragma unroll
                for (int n = 0; n < 4; n++)
                    acc[m][n] = MFMA16(a[m], bh[n], acc[m][n], 0, 0, 0);
        }
        __builtin_amdgcn_s_setprio(0);
    };

    const int NT = D / 32;

    // prologue: A(0) + B(0) staged; B(1) in flight
    DMAA(0);
    DMAB(0, 0);
    DMAB(1, 1);
    asm volatile("s_waitcnt vmcnt(6)" ::: "memory");  // A0 + B0 done, B1 in flight
    __builtin_amdgcn_sched_barrier(0);
    __builtin_amdgcn_s_barrier();
    __builtin_amdgcn_sched_barrier(0);

    for (int tt = 0; tt < NT; ++tt) {
        MFMA_PHASE(tt & 1);
        __builtin_amdgcn_sched_barrier(0);
        __builtin_amdgcn_s_barrier();  // all waves done reading ldsA + ldsB[tt&1]
        __builtin_amdgcn_sched_barrier(0);
        if (tt < NT - 1) {
            DMAA(tt + 1);  // 6 ops into the (now-free) single A buffer
            if (tt < NT - 2) {
                DMAB(tt + 2, tt & 1);  // newest 6
                asm volatile("s_waitcnt vmcnt(6)" ::: "memory");
            } else {
                asm volatile("s_waitcnt vmcnt(0)" ::: "memory");
            }
            __builtin_amdgcn_sched_barrier(0);
            __builtin_amdgcn_s_barrier();
            __builtin_amdgcn_sched_barrier(0);
        }
    }

    float csv[4];
#pragma unroll
    for (int n = 0; n < 4; n++) csv[n] = cs[col0 + wc * 64 + n * 16 + r];
#pragma unroll
    for (int m = 0; m < 4; m++)
#pragma unroll
        for (int n = 0; n < 4; n++)
#pragma unroll
            for (int j = 0; j < 4; j++) {
                size_t grow = row0 + wr * 64 + m * 16 + g * 4 + j;
                size_t gcol = col0 + wc * 64 + n * 16 + r;
                O[grow * D + gcol] = acc[m][n][j] * csv[n];
            }
}

// ================= small-ws fallback (R5-proven) =================
constexpr int BM = 128, BN = 128, LDK = 40;

template <int SCALED>
__global__ __launch_bounds__(256, 2) void gemm3(const float* __restrict__ A,
                                                const float* __restrict__ B,
                                                const float* __restrict__ rs,
                                                const float* __restrict__ ks,
                                                const float* __restrict__ cs,
                                                float* __restrict__ O) {
    __shared__ ushort Ahs[BM][LDK], Ams[BM][LDK], Als[BM][LDK];
    __shared__ ushort Bhs[BN][LDK], Bms[BN][LDK], Bls[BN][LDK];
    int t = threadIdx.x;
    int lane = t & 63, wv = t >> 6;
    int wr = wv >> 1, wc = wv & 1;
    int r = lane & 15, g = lane >> 4;
    size_t row0 = (size_t)blockIdx.y * BM;
    size_t col0 = (size_t)blockIdx.x * BN;
    int sArow = t >> 1, sAk = (t & 1) * 16, sBcol = t & 127, sBk = (t >> 7) * 16;

    f32x4 acc[4][4];
#pragma unroll
    for (int m = 0; m < 4; m++)
#pragma unroll
        for (int n = 0; n < 4; n++) acc[m][n] = (f32x4){0.f, 0.f, 0.f, 0.f};

    float av[16], bv[16];
    auto LOADT = [&](int k0) {
        const float4* pa = (const float4*)(A + (row0 + sArow) * (size_t)D + k0 + sAk);
#pragma unroll
        for (int qq = 0; qq < 4; qq++) {
            float4 w = pa[qq];
            av[qq * 4 + 0] = w.x; av[qq * 4 + 1] = w.y; av[qq * 4 + 2] = w.z; av[qq * 4 + 3] = w.w;
        }
        if (SCALED) {
            float rsv = rs[row0 + sArow];
            const float4* pk = (const float4*)(ks + k0 + sAk);
#pragma unroll
            for (int qq = 0; qq < 4; qq++) {
                float4 kk = pk[qq];
                av[qq * 4 + 0] *= rsv * kk.x; av[qq * 4 + 1] *= rsv * kk.y;
                av[qq * 4 + 2] *= rsv * kk.z; av[qq * 4 + 3] *= rsv * kk.w;
            }
        }
        const float* pb = B + ((size_t)k0 + sBk) * D + col0 + sBcol;
#pragma unroll
        for (int kk = 0; kk < 16; kk++) bv[kk] = pb[(size_t)kk * D];
    };

    LOADT(0);
    for (int kt = 0; kt < D / 32; ++kt) {
        __syncthreads();
        {
            uint hp[8], mp[8], lp[8];
#pragma unroll
            for (int j = 0; j < 8; j++) split3_pk(av[2 * j], av[2 * j + 1], hp[j], mp[j], lp[j]);
            uint4 u;
            u.x = hp[0]; u.y = hp[1]; u.z = hp[2]; u.w = hp[3]; *(uint4*)&Ahs[sArow][sAk] = u;
            u.x = hp[4]; u.y = hp[5]; u.z = hp[6]; u.w = hp[7]; *(uint4*)&Ahs[sArow][sAk + 8] = u;
            u.x = mp[0]; u.y = mp[1]; u.z = mp[2]; u.w = mp[3]; *(uint4*)&Ams[sArow][sAk] = u;
            u.x = mp[4]; u.y = mp[5]; u.z = mp[6]; u.w = mp[7]; *(uint4*)&Ams[sArow][sAk + 8] = u;
            u.x = lp[0]; u.y = lp[1]; u.z = lp[2]; u.w = lp[3]; *(uint4*)&Als[sArow][sAk] = u;
            u.x = lp[4]; u.y = lp[5]; u.z = lp[6]; u.w = lp[7]; *(uint4*)&Als[sArow][sAk + 8] = u;
        }
        {
            uint hp[8], mp[8], lp[8];
#pragma unroll
            for (int j = 0; j < 8; j++) split3_pk(bv[2 * j], bv[2 * j + 1], hp[j], mp[j], lp[j]);
            uint4 u;
            u.x = hp[0]; u.y = hp[1]; u.z = hp[2]; u.w = hp[3]; *(uint4*)&Bhs[sBcol][sBk] = u;
            u.x = hp[4]; u.y = hp[5]; u.z = hp[6]; u.w = hp[7]; *(uint4*)&Bhs[sBcol][sBk + 8] = u;
            u.x = mp[0]; u.y = mp[1]; u.z = mp[2]; u.w = mp[3]; *(uint4*)&Bms[sBcol][sBk] = u;
            u.x = mp[4]; u.y = mp[5]; u.z = mp[6]; u.w = mp[7]; *(uint4*)&Bms[sBcol][sBk + 8] = u;
            u.x = lp[0]; u.y = lp[1]; u.z = lp[2]; u.w = lp[3]; *(uint4*)&Bls[sBcol][sBk] = u;
            u.x = lp[4]; u.y = lp[5]; u.z = lp[6]; u.w = lp[7]; *(uint4*)&Bls[sBcol][sBk + 8] = u;
        }
        __syncthreads();
        if (kt + 1 < D / 32) LOADT((kt + 1) * 32);

        bf16x8 bh[4], bm[4], bl[4];
#pragma unroll
        for (int n = 0; n < 4; n++) {
            bh[n] = *(const bf16x8*)&Bhs[wc * 64 + n * 16 + r][g * 8];
            bm[n] = *(const bf16x8*)&Bms[wc * 64 + n * 16 + r][g * 8];
            bl[n] = *(const bf16x8*)&Bls[wc * 64 + n * 16 + r][g * 8];
        }
#pragma unroll
        for (int m = 0; m < 4; m++) {
            bf16x8 ah = *(const bf16x8*)&Ahs[wr * 64 + m * 16 + r][g * 8];
            bf16x8 am = *(const bf16x8*)&Ams[wr * 64 + m * 16 + r][g * 8];
            bf16x8 al = *(const bf16x8*)&Als[wr * 64 + m * 16 + r][g * 8];
#pragma unroll
            for (int n = 0; n < 4; n++) {
                acc[m][n] = MFMA16(ah, bh[n], acc[m][n], 0, 0, 0);
                acc[m][n] = MFMA16(ah, bm[n], acc[m][n], 0, 0, 0);
                acc[m][n] = MFMA16(am, bh[n], acc[m][n], 0, 0, 0);
                acc[m][n] = MFMA16(am, bm[n], acc[m][n], 0, 0, 0);
                acc[m][n] = MFMA16(ah, bl[n], acc[m][n], 0, 0, 0);
                acc[m][n] = MFMA16(al, bh[n], acc[m][n], 0, 0, 0);
            }
        }
    }
    float csv[4];
#pragma unroll
    for (int n = 0; n < 4; n++) csv[n] = cs[col0 + wc * 64 + n * 16 + r];
#pragma unroll
    for (int m = 0; m < 4; m++)
#pragma unroll
        for (int n = 0; n < 4; n++)
#pragma unroll
            for (int j = 0; j < 4; j++) {
                size_t grow = row0 + wr * 64 + m * 16 + g * 4 + j;
                size_t gcol = col0 + wc * 64 + n * 16 + r;
                O[grow * D + gcol] = acc[m][n][j] * csv[n];
            }
}

extern "C" void kernel_launch(void* const* d_in, const int* in_sizes, int n_in,
                              void* d_out, int out_size, void* d_ws, size_t ws_size,
                              hipStream_t stream) {
    const float* x = (const float*)d_in[0];
    const float* W1 = (const float*)d_in[1];
    const float* b1 = (const float*)d_in[2];
    const float* W2 = (const float*)d_in[3];
    const float* b2 = (const float*)d_in[4];
    const float* W3 = (const float*)d_in[5];
    const float* b3 = (const float*)d_in[6];

    float* out = (float*)d_out;
    float* Rout = out + D;

    char* ws = (char*)d_ws;
    float* z1 = (float*)ws;
    float* z2 = z1 + D;
    float* z3 = z2 + D;
    float* a1 = z3 + D;
    float* a2 = a1 + D;
    float* s3 = a2 + D;
    float* g2 = s3 + D;
    float* g1 = g2 + D;
    size_t smallB = (size_t)D * 8 * sizeof(float);

    const size_t PL = (size_t)D * D;                     // ushorts per plane (32 MB)
    size_t planesB = 3 * PL * sizeof(ushort);            // 96 MB
    size_t cB = (size_t)D * D * sizeof(float);           // 64 MB
    size_t need2 = smallB + 2 * planesB + 256;           // ~192.13 MB (proven available)
    size_t need1 = smallB + planesB + cB + 256;          // ~160.13 MB

    // forward pass — bit-exact numpy-f32 emulation (unchanged)
    gemv_blas8<<<(D * 8) / 256, 256, 0, stream>>>(W1, x, b1, z1, a1, 1);
    gemv_blas8<<<(D * 8) / 256, 256, 0, stream>>>(W2, a1, b2, z2, a2, 1);
    gemv_blas8<<<(D * 8) / 256, 256, 0, stream>>>(W3, a2, b3, z3, nullptr, 0);
    vecprep32<<<D / 256, 256, 0, stream>>>(z1, z2, z3, a1, a2, b3, out, s3, g2, g1);

    dim3 gg(D / 128, D / 128);
    int pgrid = (int)((PL / 8) / 256);
    if (ws_size >= need2) {
        ushort* Bpl = (ushort*)(ws + smallB);
        ushort* Cpl = Bpl + 3 * PL;
        prepBT<<<pgrid, 256, 0, stream>>>(W2, Bpl, Bpl + PL, Bpl + 2 * PL);
        gemm_bs<1, 1><<<gg, 256, 0, stream>>>(W3, Bpl, Bpl + PL, Bpl + 2 * PL,
                                              s3, g2, g1, nullptr,
                                              Cpl, Cpl + PL, Cpl + 2 * PL);
        prepBT<<<pgrid, 256, 0, stream>>>(W1, Bpl, Bpl + PL, Bpl + 2 * PL);
        gemm_ab2<<<gg, 256, 0, stream>>>(Cpl, Cpl + PL, Cpl + 2 * PL,
                                         Bpl, Bpl + PL, Bpl + 2 * PL, x, Rout);
    } else if (ws_size >= need1) {
        ushort* Bpl = (ushort*)(ws + smallB);
        float* C = (float*)(ws + smallB + planesB);
        prepBT<<<pgrid, 256, 0, stream>>>(W2, Bpl, Bpl + PL, Bpl + 2 * PL);
        gemm_bs<1, 0><<<gg, 256, 0, stream>>>(W3, Bpl, Bpl + PL, Bpl + 2 * PL,
                                              s3, g2, g1, C, nullptr, nullptr, nullptr);
        prepBT<<<pgrid, 256, 0, stream>>>(W1, Bpl, Bpl + PL, Bpl + 2 * PL);
        gemm_bs<0, 0><<<gg, 256, 0, stream>>>(C, Bpl, Bpl + PL, Bpl + 2 * PL,
                                              nullptr, nullptr, x, Rout, nullptr, nullptr, nullptr);
    } else {
        float* C = (float*)(ws + smallB);
        gemm3<1><<<gg, 256, 0, stream>>>(W3, W2, s3, g2, g1, C);
        gemm3<0><<<gg, 256, 0, stream>>>(C, W1, nullptr, nullptr, x, Rout);
    }
}